// Round 3
// baseline (509.255 us; speedup 1.0000x reference)
//
#include <hip/hip_runtime.h>

typedef unsigned short u16;
typedef unsigned int   u32;
typedef __attribute__((ext_vector_type(8))) short short8;  // 8 bf16 (4 VGPRs)
typedef __attribute__((ext_vector_type(4))) float f32x4;   // MFMA 16x16 accumulator

#define DEVI static __device__ __forceinline__

DEVI u16 f2bf(float f) {  // fp32 -> bf16 RNE
  u32 u = __float_as_uint(f);
  u32 r = (u + 0x7FFFu + ((u >> 16) & 1u)) >> 16;
  return (u16)r;
}

DEVI void gload_lds16(const void* g, void* l) {
  // async global->LDS, 16B/lane; LDS dest = wave-uniform base + lane*16
  __builtin_amdgcn_global_load_lds(
      (const __attribute__((address_space(1))) void*)g,
      (__attribute__((address_space(3))) void*)l, 16, 0, 0);
}

// ---------------- fp32 -> bf16 convert, 8 elems/thread ----------------
__global__ void __launch_bounds__(256) cvt_kernel(const float4* __restrict__ src,
                                                  uint4* __restrict__ dst, int n8) {
  int i = blockIdx.x * 256 + threadIdx.x;
  if (i >= n8) return;
  float4 a = src[2 * i], b = src[2 * i + 1];
  uint4 o;
  o.x = (u32)f2bf(a.x) | ((u32)f2bf(a.y) << 16);
  o.y = (u32)f2bf(a.z) | ((u32)f2bf(a.w) << 16);
  o.z = (u32)f2bf(b.x) | ((u32)f2bf(b.y) << 16);
  o.w = (u32)f2bf(b.z) | ((u32)f2bf(b.w) << 16);
  dst[i] = o;
}

// 4 weight matrices in one launch; blockIdx.y selects segment
__global__ void __launch_bounds__(256) cvt4_kernel(
    const float4* __restrict__ s0, const float4* __restrict__ s1,
    const float4* __restrict__ s2, const float4* __restrict__ s3,
    uint4* __restrict__ d0, uint4* __restrict__ d1,
    uint4* __restrict__ d2, uint4* __restrict__ d3, int n8) {
  int i = blockIdx.x * 256 + threadIdx.x;
  if (i >= n8) return;
  int seg = blockIdx.y;
  const float4* s = (seg == 0) ? s0 : (seg == 1) ? s1 : (seg == 2) ? s2 : s3;
  uint4* d = (seg == 0) ? d0 : (seg == 1) ? d1 : (seg == 2) ? d2 : d3;
  float4 a = s[2 * i], b = s[2 * i + 1];
  uint4 o;
  o.x = (u32)f2bf(a.x) | ((u32)f2bf(a.y) << 16);
  o.y = (u32)f2bf(a.z) | ((u32)f2bf(a.w) << 16);
  o.z = (u32)f2bf(b.x) | ((u32)f2bf(b.y) << 16);
  o.w = (u32)f2bf(b.z) | ((u32)f2bf(b.w) << 16);
  d[i] = o;
}

// ---------------- GEMM: C[M,N] = A[M,K] @ W[N,K]^T (+bias), K=2048 ----------------
// m97 structure: 128x128 tile, BK=32, 4 waves (2x2), global_load_lds staging.
// MODE 0: out bf16 (QKV cat, ldc=6144), bias segment select + q-scale on cols<2048.
// MODE 1: out fp32 (final proj, ldc=2048), bias0 only.
template <int MODE>
__global__ void __launch_bounds__(256) gemm_bt(
    const u16* __restrict__ A, const u16* __restrict__ Bw, void* __restrict__ Cp,
    const float* __restrict__ bias0, const float* __restrict__ bias1,
    const float* __restrict__ bias2, int ldc) {
  constexpr int K = 2048;
  __shared__ __align__(16) u16 As[128 * 32];
  __shared__ __align__(16) u16 Bs[128 * 32];
  const int tid = threadIdx.x, w = tid >> 6, l = tid & 63;
  const int wm = w >> 1, wn = w & 1;
  const int bm = blockIdx.x, bn = blockIdx.y;
  const char* Ab = (const char*)(A + (size_t)bm * 128 * K);
  const char* Bb = (const char*)(Bw + (size_t)bn * 128 * K);
  f32x4 acc[4][4] = {};
  for (int kt = 0; kt < K / 32; ++kt) {
#pragma unroll
    for (int q = 0; q < 2; ++q) {
      int byteoff = q * 4096 + w * 1024 + l * 16;  // position in 8KB tile
      int row = byteoff >> 6, colb = byteoff & 63; // 64B per row (32 bf16)
      gload_lds16(Ab + (size_t)row * (K * 2) + kt * 64 + colb,
                  (char*)As + q * 4096 + w * 1024);
      gload_lds16(Bb + (size_t)row * (K * 2) + kt * 64 + colb,
                  (char*)Bs + q * 4096 + w * 1024);
    }
    __syncthreads();
    short8 af[4], bf[4];
#pragma unroll
    for (int mi = 0; mi < 4; ++mi)
      af[mi] = *(const short8*)((const char*)As + (wm * 64 + mi * 16 + (l & 15)) * 64 + (l >> 4) * 16);
#pragma unroll
    for (int ni = 0; ni < 4; ++ni)
      bf[ni] = *(const short8*)((const char*)Bs + (wn * 64 + ni * 16 + (l & 15)) * 64 + (l >> 4) * 16);
#pragma unroll
    for (int mi = 0; mi < 4; ++mi)
#pragma unroll
      for (int ni = 0; ni < 4; ++ni)
        acc[mi][ni] = __builtin_amdgcn_mfma_f32_16x16x32_bf16(af[mi], bf[ni], acc[mi][ni], 0, 0, 0);
    __syncthreads();
  }
  // epilogue: C/D layout col=lane&15, row=(lane>>4)*4+reg (m89-verified)
#pragma unroll
  for (int mi = 0; mi < 4; ++mi) {
    int grow = bm * 128 + wm * 64 + mi * 16 + ((l >> 4) << 2);
#pragma unroll
    for (int ni = 0; ni < 4; ++ni) {
      int gcol = bn * 128 + wn * 64 + ni * 16 + (l & 15);
#pragma unroll
      for (int j = 0; j < 4; ++j) {
        float v = acc[mi][ni][j];
        if (MODE == 0) {
          int seg = gcol >> 11;  // 0=q 1=k 2=v
          const float* bp = (seg == 0) ? bias0 : (seg == 1 ? bias1 : bias2);
          v += bp[gcol & 2047];
          if (seg == 0) v *= 0.08838834764831845f;  // HEAD_DIM^-0.5
          ((u16*)Cp)[(size_t)(grow + j) * ldc + gcol] = f2bf(v);
        } else {
          ((float*)Cp)[(size_t)(grow + j) * ldc + gcol] = v + bias0[gcol];
        }
      }
    }
  }
}

// ---------------- Flash attention, bf16 MFMA 16x16x32 ----------------
// Block: 4 waves x 16 q-rows = 64 q rows; KV tile = 64. grid = B*H*(S/64) = 1024.
__global__ void __launch_bounds__(256) attn_kernel(const u16* __restrict__ qkv,
                                                   const float* __restrict__ amask,
                                                   u16* __restrict__ ctx) {
  __shared__ __align__(16) char KtB[64 * 256];      // K tile, rows 256B, XOR-swizzled
  __shared__ __align__(16) char VtB[128 * 128];     // V^T tile, rows 128B, XOR-swizzled
  __shared__ __align__(16) char PbB[4][16 * 128];   // per-wave P, XOR-swizzled
  const int tid = threadIdx.x, w = tid >> 6, l = tid & 63;
  const int l15 = l & 15, l4 = l >> 4;
  const int qt = blockIdx.x & 31, h = (blockIdx.x >> 5) & 15, b = (int)(blockIdx.x >> 9);
  const int ld = 6144;
  // Q fragments (once): A-frag lane l holds Q[row=l&15][d=(l>>4)*8 ..+8] per 32-d chunk
  const u16* qp = qkv + (size_t)(b * 2048 + qt * 64 + w * 16 + l15) * ld + h * 128;
  short8 qf[4];
#pragma unroll
  for (int dc = 0; dc < 4; ++dc) qf[dc] = *(const short8*)(qp + dc * 32 + l4 * 8);
  f32x4 o_[8] = {};
  float m_[4], s_[4];
#pragma unroll
  for (int j = 0; j < 4; ++j) { m_[j] = -INFINITY; s_[j] = 0.f; }
  const u16* kbase = qkv + (size_t)b * 2048 * ld + 2048 + h * 128;
  const u16* vbase = qkv + (size_t)b * 2048 * ld + 4096 + h * 128;
  const float* mbase = amask + b * 2048;
  const int kr = tid >> 2, c0 = (tid & 3) * 32;       // K staging: row kr, 32-elem chunk
  const int kb = (tid & 15) * 4, dvb = (tid >> 4) * 8; // V staging: 4 k-rows x 8 dv
  for (int t = 0; t < 32; ++t) {
    const int k0 = t * 64;
    __syncthreads();  // prior tile's reads complete before overwrite
    {  // stage K (row-major, swizzled)
      const u16* kg = kbase + (size_t)(k0 + kr) * ld + c0;
      char* drow = KtB + kr * 256;
      const int sw = (kr & 7) << 4;
#pragma unroll
      for (int u = 0; u < 4; ++u)
        *(uint4*)(drow + ((c0 * 2 + u * 16) ^ sw)) = *(const uint4*)(kg + u * 8);
      // stage V transposed (swizzled): pack 4 consecutive k per 8B write
      uint4 vr[4];
#pragma unroll
      for (int r = 0; r < 4; ++r)
        vr[r] = *(const uint4*)(vbase + (size_t)(k0 + kb + r) * ld + dvb);
#pragma unroll
      for (int dvi = 0; dvi < 8; ++dvi) {
        int dv = dvb + dvi;
        u32 lo = (u32)((const u16*)&vr[0])[dvi] | ((u32)((const u16*)&vr[1])[dvi] << 16);
        u32 hi = (u32)((const u16*)&vr[2])[dvi] | ((u32)((const u16*)&vr[3])[dvi] << 16);
        uint2 pk; pk.x = lo; pk.y = hi;
        *(uint2*)(VtB + dv * 128 + ((kb * 2) ^ ((dv & 7) << 4))) = pk;
      }
    }
    __syncthreads();
    // S = Q K^T : 4 k-chunk frags x 4 d-step MFMAs
    f32x4 s[4] = {};
#pragma unroll
    for (int kc = 0; kc < 4; ++kc) {
      const int krow = kc * 16 + l15;
      const char* krp = KtB + krow * 256;
      const int sw = (krow & 7) << 4;
#pragma unroll
      for (int dc = 0; dc < 4; ++dc) {
        short8 kf = *(const short8*)(krp + ((dc * 64 + l4 * 16) ^ sw));
        s[kc] = __builtin_amdgcn_mfma_f32_16x16x32_bf16(qf[dc], kf, s[kc], 0, 0, 0);
      }
    }
    // additive mask: col = kc*16 + (l&15)
#pragma unroll
    for (int kc = 0; kc < 4; ++kc) {
      float mv = mbase[k0 + kc * 16 + l15];
      float am = (1.0f - mv) * -3.402823466e38f;
#pragma unroll
      for (int j = 0; j < 4; ++j) s[kc][j] += am;
    }
    // online softmax; rows live in 16-lane groups -> shfl_xor {1,2,4,8}
    float fct[4], rs[4];
#pragma unroll
    for (int j = 0; j < 4; ++j) {
      float v = fmaxf(fmaxf(s[0][j], s[1][j]), fmaxf(s[2][j], s[3][j]));
      v = fmaxf(v, __shfl_xor(v, 1));
      v = fmaxf(v, __shfl_xor(v, 2));
      v = fmaxf(v, __shfl_xor(v, 4));
      v = fmaxf(v, __shfl_xor(v, 8));
      float mn = fmaxf(m_[j], v);
      fct[j] = __expf(m_[j] - mn);
      m_[j] = mn;
      rs[j] = 0.f;
    }
#pragma unroll
    for (int kc = 0; kc < 4; ++kc) {
      const int kk = kc * 16 + l15;
#pragma unroll
      for (int j = 0; j < 4; ++j) {
        float p = __expf(s[kc][j] - m_[j]);
        rs[j] += p;
        int qq = l4 * 4 + j;  // C-layout row -> P row
        *(u16*)(PbB[w] + qq * 128 + ((kk * 2) ^ ((qq & 7) << 4))) = f2bf(p);
      }
    }
#pragma unroll
    for (int j = 0; j < 4; ++j) {
      float v = rs[j];
      v += __shfl_xor(v, 1);
      v += __shfl_xor(v, 2);
      v += __shfl_xor(v, 4);
      v += __shfl_xor(v, 8);
      s_[j] = s_[j] * fct[j] + v;
    }
#pragma unroll
    for (int dvc = 0; dvc < 8; ++dvc)
#pragma unroll
      for (int j = 0; j < 4; ++j) o_[dvc][j] *= fct[j];
    // O += P V  (P A-frags from wave-private LDS; V B-frags from V^T tile)
    short8 pa[2];
    {
      const int swp = (l15 & 7) << 4;
#pragma unroll
      for (int kh = 0; kh < 2; ++kh)
        pa[kh] = *(const short8*)(PbB[w] + l15 * 128 + ((kh * 64 + l4 * 16) ^ swp));
    }
#pragma unroll
    for (int dvc = 0; dvc < 8; ++dvc) {
      const int dv = dvc * 16 + l15;
      const char* vrp = VtB + dv * 128;
      const int swv = (dv & 7) << 4;
#pragma unroll
      for (int kh = 0; kh < 2; ++kh) {
        short8 vf = *(const short8*)(vrp + ((kh * 64 + l4 * 16) ^ swv));
        o_[dvc] = __builtin_amdgcn_mfma_f32_16x16x32_bf16(pa[kh], vf, o_[dvc], 0, 0, 0);
      }
    }
  }
  float inv[4];
#pragma unroll
  for (int j = 0; j < 4; ++j) inv[j] = 1.0f / s_[j];
  u16* crow = ctx + (size_t)(b * 2048 + qt * 64 + w * 16 + l4 * 4) * 2048 + h * 128;
#pragma unroll
  for (int dvc = 0; dvc < 8; ++dvc)
#pragma unroll
    for (int j = 0; j < 4; ++j)
      crow[(size_t)j * 2048 + dvc * 16 + l15] = f2bf(o_[dvc][j] * inv[j]);
}

// ---------------- launcher ----------------
extern "C" void kernel_launch(void* const* d_in, const int* in_sizes, int n_in,
                              void* d_out, int out_size, void* d_ws, size_t ws_size,
                              hipStream_t stream) {
  const float* hs    = (const float*)d_in[0];
  const float* amask = (const float*)d_in[1];
  const float* Wq    = (const float*)d_in[2];
  const float* bq    = (const float*)d_in[3];
  const float* Wk    = (const float*)d_in[4];
  const float* bk    = (const float*)d_in[5];
  const float* Wv    = (const float*)d_in[6];
  const float* bv    = (const float*)d_in[7];
  const float* Wo    = (const float*)d_in[8];
  const float* bo    = (const float*)d_in[9];
  float* out = (float*)d_out;

  char* ws = (char*)d_ws;
  u16* hiddenB = (u16*)ws;                                          // [4096][2048] bf16
  u16* wcatB   = (u16*)(ws + 16777216ull);                          // [6144][2048] bf16 (Wq;Wk;Wv)
  u16* woB     = (u16*)(ws + 16777216ull + 25165824ull);            // [2048][2048] bf16
  u16* qkvB    = (u16*)(ws + 16777216ull + 25165824ull + 8388608ull);        // [4096][6144] bf16
  u16* ctxB    = (u16*)(ws + 16777216ull + 25165824ull + 8388608ull + 50331648ull);  // [4096][2048] bf16

  cvt_kernel<<<4096, 256, 0, stream>>>((const float4*)hs, (uint4*)hiddenB, 1048576);
  cvt4_kernel<<<dim3(2048, 4), 256, 0, stream>>>(
      (const float4*)Wq, (const float4*)Wk, (const float4*)Wv, (const float4*)Wo,
      (uint4*)wcatB, (uint4*)(wcatB + 2048 * 2048), (uint4*)(wcatB + 2 * 2048 * 2048),
      (uint4*)woB, 524288);

  gemm_bt<0><<<dim3(32, 48), 256, 0, stream>>>(hiddenB, wcatB, qkvB, bq, bk, bv, 6144);
  attn_kernel<<<1024, 256, 0, stream>>>(qkvB, amask, ctxB);
  gemm_bt<1><<<dim3(32, 16), 256, 0, stream>>>(ctxB, woB, out, bo, nullptr, nullptr, 2048);
}

// Round 4
// 429.080 us; speedup vs baseline: 1.1869x; 1.1869x over previous
//
#include <hip/hip_runtime.h>

typedef unsigned short u16;
typedef unsigned int   u32;
typedef __attribute__((ext_vector_type(8))) short short8;  // 8 bf16 (4 VGPRs)
typedef __attribute__((ext_vector_type(4))) float f32x4;   // MFMA 16x16 accumulator

#define DEVI static __device__ __forceinline__

DEVI u16 f2bf(float f) {  // fp32 -> bf16 RNE
  u32 u = __float_as_uint(f);
  u32 r = (u + 0x7FFFu + ((u >> 16) & 1u)) >> 16;
  return (u16)r;
}

DEVI void gload_lds16(const void* g, void* l) {
  // async global->LDS, 16B/lane; LDS dest = wave-uniform base + lane*16
  __builtin_amdgcn_global_load_lds(
      (const __attribute__((address_space(1))) void*)g,
      (__attribute__((address_space(3))) void*)l, 16, 0, 0);
}

// ---------------- fp32 -> bf16 convert, 8 elems/thread ----------------
__global__ void __launch_bounds__(256) cvt_kernel(const float4* __restrict__ src,
                                                  uint4* __restrict__ dst, int n8) {
  int i = blockIdx.x * 256 + threadIdx.x;
  if (i >= n8) return;
  float4 a = src[2 * i], b = src[2 * i + 1];
  uint4 o;
  o.x = (u32)f2bf(a.x) | ((u32)f2bf(a.y) << 16);
  o.y = (u32)f2bf(a.z) | ((u32)f2bf(a.w) << 16);
  o.z = (u32)f2bf(b.x) | ((u32)f2bf(b.y) << 16);
  o.w = (u32)f2bf(b.z) | ((u32)f2bf(b.w) << 16);
  dst[i] = o;
}

// 4 weight matrices in one launch; blockIdx.y selects segment
__global__ void __launch_bounds__(256) cvt4_kernel(
    const float4* __restrict__ s0, const float4* __restrict__ s1,
    const float4* __restrict__ s2, const float4* __restrict__ s3,
    uint4* __restrict__ d0, uint4* __restrict__ d1,
    uint4* __restrict__ d2, uint4* __restrict__ d3, int n8) {
  int i = blockIdx.x * 256 + threadIdx.x;
  if (i >= n8) return;
  int seg = blockIdx.y;
  const float4* s = (seg == 0) ? s0 : (seg == 1) ? s1 : (seg == 2) ? s2 : s3;
  uint4* d = (seg == 0) ? d0 : (seg == 1) ? d1 : (seg == 2) ? d2 : d3;
  float4 a = s[2 * i], b = s[2 * i + 1];
  uint4 o;
  o.x = (u32)f2bf(a.x) | ((u32)f2bf(a.y) << 16);
  o.y = (u32)f2bf(a.z) | ((u32)f2bf(a.w) << 16);
  o.z = (u32)f2bf(b.x) | ((u32)f2bf(b.y) << 16);
  o.w = (u32)f2bf(b.z) | ((u32)f2bf(b.w) << 16);
  d[i] = o;
}

// ---------------- GEMM: C[M,N] = A[M,K] @ W[N,K]^T (+bias), K=2048 ----------------
// m97 structure: 128x128 tile, BK=32, 4 waves (2x2), global_load_lds staging.
template <int MODE>
__global__ void __launch_bounds__(256) gemm_bt(
    const u16* __restrict__ A, const u16* __restrict__ Bw, void* __restrict__ Cp,
    const float* __restrict__ bias0, const float* __restrict__ bias1,
    const float* __restrict__ bias2, int ldc) {
  constexpr int K = 2048;
  __shared__ __align__(16) u16 As[128 * 32];
  __shared__ __align__(16) u16 Bs[128 * 32];
  const int tid = threadIdx.x, w = tid >> 6, l = tid & 63;
  const int wm = w >> 1, wn = w & 1;
  const int bm = blockIdx.x, bn = blockIdx.y;
  const char* Ab = (const char*)(A + (size_t)bm * 128 * K);
  const char* Bb = (const char*)(Bw + (size_t)bn * 128 * K);
  f32x4 acc[4][4] = {};
  for (int kt = 0; kt < K / 32; ++kt) {
#pragma unroll
    for (int q = 0; q < 2; ++q) {
      int byteoff = q * 4096 + w * 1024 + l * 16;  // position in 8KB tile
      int row = byteoff >> 6, colb = byteoff & 63; // 64B per row (32 bf16)
      gload_lds16(Ab + (size_t)row * (K * 2) + kt * 64 + colb,
                  (char*)As + q * 4096 + w * 1024);
      gload_lds16(Bb + (size_t)row * (K * 2) + kt * 64 + colb,
                  (char*)Bs + q * 4096 + w * 1024);
    }
    __syncthreads();
    short8 af[4], bf[4];
#pragma unroll
    for (int mi = 0; mi < 4; ++mi)
      af[mi] = *(const short8*)((const char*)As + (wm * 64 + mi * 16 + (l & 15)) * 64 + (l >> 4) * 16);
#pragma unroll
    for (int ni = 0; ni < 4; ++ni)
      bf[ni] = *(const short8*)((const char*)Bs + (wn * 64 + ni * 16 + (l & 15)) * 64 + (l >> 4) * 16);
#pragma unroll
    for (int mi = 0; mi < 4; ++mi)
#pragma unroll
      for (int ni = 0; ni < 4; ++ni)
        acc[mi][ni] = __builtin_amdgcn_mfma_f32_16x16x32_bf16(af[mi], bf[ni], acc[mi][ni], 0, 0, 0);
    __syncthreads();
  }
#pragma unroll
  for (int mi = 0; mi < 4; ++mi) {
    int grow = bm * 128 + wm * 64 + mi * 16 + ((l >> 4) << 2);
#pragma unroll
    for (int ni = 0; ni < 4; ++ni) {
      int gcol = bn * 128 + wn * 64 + ni * 16 + (l & 15);
#pragma unroll
      for (int j = 0; j < 4; ++j) {
        float v = acc[mi][ni][j];
        if (MODE == 0) {
          int seg = gcol >> 11;  // 0=q 1=k 2=v
          const float* bp = (seg == 0) ? bias0 : (seg == 1 ? bias1 : bias2);
          v += bp[gcol & 2047];
          if (seg == 0) v *= 0.08838834764831845f;  // HEAD_DIM^-0.5
          ((u16*)Cp)[(size_t)(grow + j) * ldc + gcol] = f2bf(v);
        } else {
          ((float*)Cp)[(size_t)(grow + j) * ldc + gcol] = v + bias0[gcol];
        }
      }
    }
  }
}

// ---------------- Flash attention v2: swapped QK^T, 2 q-groups/wave ----------------
// Block: 4 waves x 32 q-rows = 128 q rows; KV tile = 64. grid = B*H*(S/128) = 512.
// Swapped mfma(K,Q): C[row=k=(l>>4)*4+j (+16kc)][col=q=l&15] -> softmax is lane-local.
__global__ void __launch_bounds__(256, 2) attn_kernel(const u16* __restrict__ qkv,
                                                      const float* __restrict__ amask,
                                                      u16* __restrict__ ctx) {
  __shared__ __align__(16) char KtB[64 * 256];      // K tile, rows 256B, XOR-swizzled
  __shared__ __align__(16) char VtB[128 * 128];     // V^T tile, rows 128B, XOR-swizzled
  __shared__ __align__(16) char PbB[4][2][2048];    // per-wave,q-group P [16q][64k], swizzled
  const int tid = threadIdx.x, w = tid >> 6, l = tid & 63;
  const int l15 = l & 15, l4 = l >> 4;
  const int qt = blockIdx.x & 15, h = (blockIdx.x >> 4) & 15, b = (int)(blockIdx.x >> 8);
  const int ld = 6144;
  const int swq = (l15 & 7) << 4;  // P-lds swizzle for this lane's q-row
  // Q B-frags (once): lane holds col=q=l15, d-elems l4*8..+8 per 32-d chunk
  short8 qf[2][4];
#pragma unroll
  for (int qg = 0; qg < 2; ++qg) {
    const u16* qp = qkv + (size_t)(b * 2048 + qt * 128 + w * 32 + qg * 16 + l15) * ld + h * 128;
#pragma unroll
    for (int dc = 0; dc < 4; ++dc) qf[qg][dc] = *(const short8*)(qp + dc * 32 + l4 * 8);
  }
  f32x4 o_[2][8] = {};
  float m_[2] = {-INFINITY, -INFINITY}, s_[2] = {0.f, 0.f};
  const u16* kbase = qkv + (size_t)b * 2048 * ld + 2048 + h * 128;
  const u16* vbase = qkv + (size_t)b * 2048 * ld + 4096 + h * 128;
  const float* mbase = amask + b * 2048;
  const int kr = tid >> 2, c0 = (tid & 3) * 32;        // K staging: row kr, 32-elem chunk
  const int kb = (tid & 15) * 4, dvb = (tid >> 4) * 8; // V staging: 4 k-rows x 8 dv
  for (int t = 0; t < 32; ++t) {
    const int k0 = t * 64;
    __syncthreads();  // prior tile's reads complete before overwrite
    {  // stage K (row-major, swizzled)
      const u16* kg = kbase + (size_t)(k0 + kr) * ld + c0;
      char* drow = KtB + kr * 256;
      const int sw = (kr & 7) << 4;
#pragma unroll
      for (int u = 0; u < 4; ++u)
        *(uint4*)(drow + ((c0 * 2 + u * 16) ^ sw)) = *(const uint4*)(kg + u * 8);
      // stage V transposed (swizzled): pack 4 consecutive k per 8B write
      uint4 vr[4];
#pragma unroll
      for (int r = 0; r < 4; ++r)
        vr[r] = *(const uint4*)(vbase + (size_t)(k0 + kb + r) * ld + dvb);
#pragma unroll
      for (int dvi = 0; dvi < 8; ++dvi) {
        int dv = dvb + dvi;
        u32 lo = (u32)((const u16*)&vr[0])[dvi] | ((u32)((const u16*)&vr[1])[dvi] << 16);
        u32 hi = (u32)((const u16*)&vr[2])[dvi] | ((u32)((const u16*)&vr[3])[dvi] << 16);
        uint2 pk; pk.x = lo; pk.y = hi;
        *(uint2*)(VtB + dv * 128 + ((kb * 2) ^ ((dv & 7) << 4))) = pk;
      }
    }
    __syncthreads();
    // mask (per-k additive, shared across q-groups): k = kc*16 + l4*4 + j
    float4 amv[4];
#pragma unroll
    for (int kc = 0; kc < 4; ++kc) {
      float4 mv = *(const float4*)(mbase + k0 + kc * 16 + l4 * 4);
      amv[kc].x = (1.0f - mv.x) * -3.402823466e38f;
      amv[kc].y = (1.0f - mv.y) * -3.402823466e38f;
      amv[kc].z = (1.0f - mv.z) * -3.402823466e38f;
      amv[kc].w = (1.0f - mv.w) * -3.402823466e38f;
    }
    // S^T = K Q^T : kf A-frags shared across both q-groups
    f32x4 sA[2][4];
#pragma unroll
    for (int kc = 0; kc < 4; ++kc) {
      const int krow = kc * 16 + l15;
      const char* krp = KtB + krow * 256;
      const int sw = (krow & 7) << 4;
      short8 kf[4];
#pragma unroll
      for (int dc = 0; dc < 4; ++dc)
        kf[dc] = *(const short8*)(krp + ((dc * 64 + l4 * 16) ^ sw));
#pragma unroll
      for (int qg = 0; qg < 2; ++qg) {
        f32x4 tacc = {0.f, 0.f, 0.f, 0.f};
#pragma unroll
        for (int dc = 0; dc < 4; ++dc)
          tacc = __builtin_amdgcn_mfma_f32_16x16x32_bf16(kf[dc], qf[qg][dc], tacc, 0, 0, 0);
        sA[qg][kc] = tacc;
      }
    }
    // online softmax per q-group: lane owns 16 of 64 k's for q=l15
    float fct[2];
#pragma unroll
    for (int qg = 0; qg < 2; ++qg) {
      float pm = -INFINITY;
#pragma unroll
      for (int kc = 0; kc < 4; ++kc) {
        sA[qg][kc][0] += amv[kc].x; sA[qg][kc][1] += amv[kc].y;
        sA[qg][kc][2] += amv[kc].z; sA[qg][kc][3] += amv[kc].w;
#pragma unroll
        for (int j = 0; j < 4; ++j) pm = fmaxf(pm, sA[qg][kc][j]);
      }
      pm = fmaxf(pm, __shfl_xor(pm, 16));
      pm = fmaxf(pm, __shfl_xor(pm, 32));
      float mn = fmaxf(m_[qg], pm);
      fct[qg] = __expf(m_[qg] - mn);
      m_[qg] = mn;
      float rs = 0.f;
#pragma unroll
      for (int kc = 0; kc < 4; ++kc) {
#pragma unroll
        for (int j = 0; j < 4; ++j) {
          float p = __expf(sA[qg][kc][j] - mn);
          rs += p;
          sA[qg][kc][j] = p;
        }
        u32 lo = (u32)f2bf(sA[qg][kc][0]) | ((u32)f2bf(sA[qg][kc][1]) << 16);
        u32 hi = (u32)f2bf(sA[qg][kc][2]) | ((u32)f2bf(sA[qg][kc][3]) << 16);
        uint2 pk; pk.x = lo; pk.y = hi;
        *(uint2*)(PbB[w][qg] + l15 * 128 + ((kc * 32 + l4 * 8) ^ swq)) = pk;
      }
      rs += __shfl_xor(rs, 16);
      rs += __shfl_xor(rs, 32);
      s_[qg] = s_[qg] * fct[qg] + rs;
    }
    // rescale O (fct lives per q=l15; O rows are q=l4*4+j -> broadcast)
#pragma unroll
    for (int qg = 0; qg < 2; ++qg) {
      float fq[4];
#pragma unroll
      for (int j = 0; j < 4; ++j) fq[j] = __shfl(fct[qg], l4 * 4 + j);
#pragma unroll
      for (int dvc = 0; dvc < 8; ++dvc)
#pragma unroll
        for (int j = 0; j < 4; ++j) o_[qg][dvc][j] *= fq[j];
    }
    // O += P V : pa A-frags (row=q=l15, k-elems l4*8..+8) from wave-private LDS
    short8 pa[2][2];
#pragma unroll
    for (int qg = 0; qg < 2; ++qg)
#pragma unroll
      for (int kh = 0; kh < 2; ++kh)
        pa[qg][kh] = *(const short8*)(PbB[w][qg] + l15 * 128 + ((kh * 64 + l4 * 16) ^ swq));
#pragma unroll
    for (int dvc = 0; dvc < 8; ++dvc) {
      const int dv = dvc * 16 + l15;
      const char* vrp = VtB + dv * 128;
      const int swv = (dv & 7) << 4;
#pragma unroll
      for (int kh = 0; kh < 2; ++kh) {
        short8 vf = *(const short8*)(vrp + ((kh * 64 + l4 * 16) ^ swv));
#pragma unroll
        for (int qg = 0; qg < 2; ++qg)
          o_[qg][dvc] = __builtin_amdgcn_mfma_f32_16x16x32_bf16(pa[qg][kh], vf, o_[qg][dvc], 0, 0, 0);
      }
    }
  }
  // epilogue: O rows q = l4*4+j, cols dv = dvc*16+l15; 1/s_ lives per q=l15
#pragma unroll
  for (int qg = 0; qg < 2; ++qg) {
    float inv = 1.0f / s_[qg];
    float iq[4];
#pragma unroll
    for (int j = 0; j < 4; ++j) iq[j] = __shfl(inv, l4 * 4 + j);
    u16* crow = ctx + (size_t)(b * 2048 + qt * 128 + w * 32 + qg * 16 + l4 * 4) * 2048 + h * 128;
#pragma unroll
    for (int dvc = 0; dvc < 8; ++dvc)
#pragma unroll
      for (int j = 0; j < 4; ++j)
        crow[(size_t)j * 2048 + dvc * 16 + l15] = f2bf(o_[qg][dvc][j] * iq[j]);
  }
}

// ---------------- launcher ----------------
extern "C" void kernel_launch(void* const* d_in, const int* in_sizes, int n_in,
                              void* d_out, int out_size, void* d_ws, size_t ws_size,
                              hipStream_t stream) {
  const float* hs    = (const float*)d_in[0];
  const float* amask = (const float*)d_in[1];
  const float* Wq    = (const float*)d_in[2];
  const float* bq    = (const float*)d_in[3];
  const float* Wk    = (const float*)d_in[4];
  const float* bk    = (const float*)d_in[5];
  const float* Wv    = (const float*)d_in[6];
  const float* bv    = (const float*)d_in[7];
  const float* Wo    = (const float*)d_in[8];
  const float* bo    = (const float*)d_in[9];
  float* out = (float*)d_out;

  char* ws = (char*)d_ws;
  u16* hiddenB = (u16*)ws;                                          // [4096][2048] bf16
  u16* wcatB   = (u16*)(ws + 16777216ull);                          // [6144][2048] bf16 (Wq;Wk;Wv)
  u16* woB     = (u16*)(ws + 16777216ull + 25165824ull);            // [2048][2048] bf16
  u16* qkvB    = (u16*)(ws + 16777216ull + 25165824ull + 8388608ull);        // [4096][6144] bf16
  u16* ctxB    = (u16*)(ws + 16777216ull + 25165824ull + 8388608ull + 50331648ull);  // [4096][2048] bf16

  cvt_kernel<<<4096, 256, 0, stream>>>((const float4*)hs, (uint4*)hiddenB, 1048576);
  cvt4_kernel<<<dim3(2048, 4), 256, 0, stream>>>(
      (const float4*)Wq, (const float4*)Wk, (const float4*)Wv, (const float4*)Wo,
      (uint4*)wcatB, (uint4*)(wcatB + 2048 * 2048), (uint4*)(wcatB + 2 * 2048 * 2048),
      (uint4*)woB, 524288);

  gemm_bt<0><<<dim3(32, 48), 256, 0, stream>>>(hiddenB, wcatB, qkvB, bq, bk, bv, 6144);
  attn_kernel<<<512, 256, 0, stream>>>(qkvB, amask, ctxB);
  gemm_bt<1><<<dim3(32, 16), 256, 0, stream>>>(ctxB, woB, out, bo, nullptr, nullptr, 2048);
}